// Round 17
// baseline (871.956 us; speedup 1.0000x reference)
//
#include <hip/hip_runtime.h>
#include <hip/hip_bf16.h>
#include <stdint.h>

typedef __bf16 bf16_t;
typedef __bf16 bf16x8 __attribute__((ext_vector_type(8)));
typedef __bf16 bf16x4 __attribute__((ext_vector_type(4)));
typedef float f32x4 __attribute__((ext_vector_type(4)));

#define T_TOK 4096
#define DIM   1024
#define HID   2048
#define NE    8
#define MAXT  72   // max 128-row m-tiles: 8192/128 + 8

// async global->LDS, 16B per lane, LDS dest = wave-uniform base + lane*16
__device__ __forceinline__ void gload_lds16(const void* g, void* l) {
  __builtin_amdgcn_global_load_lds(
      (const __attribute__((address_space(1))) unsigned int*)g,
      (__attribute__((address_space(3))) unsigned int*)l, 16, 0, 0);
}

// big-tile transpose: [256k][128n] f32 -> out[n][k] bf16 (512B read runs, 512B write runs)
__device__ __forceinline__ void wt_tile(const float* __restrict__ in,
                                        bf16_t* __restrict__ out,
                                        int K, int N, int e, int ky, int nx,
                                        bf16_t (*tileT)[264]) {
  const size_t eoff = (size_t)e * K * N;
  const int k0 = ky * 256, n0 = nx * 128;
  const int tid = threadIdx.x;
  const int kl = tid >> 5;          // 0..7
  const int n4 = (tid & 31) * 4;    // 0..124
#pragma unroll
  for (int it = 0; it < 32; ++it) {
    int k = it * 8 + kl;
    float4 v = *(const float4*)(in + eoff + (size_t)(k0 + k) * N + n0 + n4);
    tileT[n4 + 0][k] = (bf16_t)v.x;
    tileT[n4 + 1][k] = (bf16_t)v.y;
    tileT[n4 + 2][k] = (bf16_t)v.z;
    tileT[n4 + 3][k] = (bf16_t)v.w;
  }
  __syncthreads();
  const int kc = (tid & 31) * 8;    // 0..248
#pragma unroll
  for (int it = 0; it < 16; ++it) {
    int n = it * 8 + kl;
    bf16x8 o = *(const bf16x8*)(&tileT[n][kc]);
    *(bf16x8*)(out + eoff + (size_t)(n0 + n) * K + k0 + kc) = o;
  }
}

// ---------------- prepA: w3^T (512 blocks) + router(+x->bf16) (1024 blocks) ----------------
__global__ __launch_bounds__(256) void k_prepA(
    const float* __restrict__ x, const float* __restrict__ rw,
    const float* __restrict__ rb, const float* __restrict__ w3,
    bf16_t* __restrict__ xb, bf16_t* __restrict__ w3t,
    int* __restrict__ counts, int* __restrict__ top_i, float* __restrict__ top_w,
    float* __restrict__ aux) {
  __shared__ bf16_t tileT[128][264];
  const int b = blockIdx.x;
  if (b < 512) {                // w3^T: K=2048 (8 ky), N=1024 (8 nx)
    int e = b >> 6, rem = b & 63;
    wt_tile(w3, w3t, HID, DIM, e, rem >> 3, rem & 7, tileT);
    return;
  }
  // ---- router + x->bf16 ----
  int t = (b - 512) * 4 + (threadIdx.x >> 6);
  int lane = threadIdx.x & 63;
  const float* xt = x + (size_t)t * DIM;
  float acc[8] = {0.f,0.f,0.f,0.f,0.f,0.f,0.f,0.f};
#pragma unroll
  for (int it = 0; it < 4; ++it) {
    int i = (it * 64 + lane) * 4;
    float4 xv = *(const float4*)(xt + i);
    bf16x4 o;
    o[0] = (bf16_t)xv.x; o[1] = (bf16_t)xv.y; o[2] = (bf16_t)xv.z; o[3] = (bf16_t)xv.w;
    *(bf16x4*)(xb + (size_t)t * DIM + i) = o;
#pragma unroll
    for (int c = 0; c < 4; ++c) {
      float v = (c == 0) ? xv.x : (c == 1) ? xv.y : (c == 2) ? xv.z : xv.w;
      float4 r0 = *(const float4*)(rw + (size_t)(i + c) * 8);
      float4 r1 = *(const float4*)(rw + (size_t)(i + c) * 8 + 4);
      acc[0] += v * r0.x; acc[1] += v * r0.y; acc[2] += v * r0.z; acc[3] += v * r0.w;
      acc[4] += v * r1.x; acc[5] += v * r1.y; acc[6] += v * r1.z; acc[7] += v * r1.w;
    }
  }
#pragma unroll
  for (int m = 32; m >= 1; m >>= 1) {
#pragma unroll
    for (int e = 0; e < 8; ++e) acc[e] += __shfl_xor(acc[e], m, 64);
  }
  if (lane == 0) {
    float s[8]; float sumsq = 0.f;
#pragma unroll
    for (int e = 0; e < 8; ++e) {
      float lg = acc[e] + rb[e];
      sumsq += lg * lg;
      s[e] = 1.f / (1.f + __expf(-lg));
    }
    int i1 = 0;
#pragma unroll
    for (int e = 1; e < 8; ++e) if (s[e] > s[i1]) i1 = e;
    int i2 = (i1 == 0) ? 1 : 0;
#pragma unroll
    for (int e = 0; e < 8; ++e) if (e != i1 && s[e] > s[i2]) i2 = e;
    float v1 = s[i1], v2 = s[i2];
    float den = v1 + v2 + 1e-6f;
    top_i[2 * t]     = i1; top_i[2 * t + 1] = i2;
    top_w[2 * t]     = v1 / den;
    top_w[2 * t + 1] = v2 / den;
    atomicAdd(&counts[i1], 1);
    atomicAdd(&counts[i2], 1);
    atomicAdd(aux, 0.01f * sumsq * (1.f / 32768.f));
  }
}

// ---------------- plan: base offsets + m-tile table ----------------
__global__ void k_plan(const int* __restrict__ counts, int* __restrict__ base,
                       int* __restrict__ tile_e, int* __restrict__ tile_m0) {
  if (threadIdx.x == 0) {
    int s = 0, nt = 0;
    for (int e = 0; e < NE; ++e) {
      base[e] = s;
      int c = counts[e];
      for (int m0 = 0; m0 < c; m0 += 128) { tile_e[nt] = e; tile_m0[nt] = m0; ++nt; }
      s += c;
    }
    for (; nt < MAXT; ++nt) tile_e[nt] = -1;
  }
}

// ---------------- gather tokens into per-expert slot lists ----------------
__global__ __launch_bounds__(256) void k_gather(const int* __restrict__ top_i,
    const float* __restrict__ top_w, const int* __restrict__ base,
    int* __restrict__ fill, int* __restrict__ slot_token, float* __restrict__ slot_wt,
    int* __restrict__ slot_of) {
  int t = blockIdx.x * 256 + threadIdx.x;
  if (t >= T_TOK) return;
#pragma unroll
  for (int j = 0; j < 2; ++j) {
    int e = top_i[2 * t + j];
    int p = atomicAdd(&fill[e], 1);
    int g = base[e] + p;
    slot_token[g] = t;
    slot_wt[g]    = top_w[2 * t + j];
    slot_of[2 * t + j] = g;
  }
}

// ---------------- FUSED: w12^T producer blocks + gemm1 consumer blocks ----------------
// grid (32, 32+MAXT). y<32: w12T tile id=y*32+x (1024 tiles, dispatched FIRST).
//   tile (e, ky, nx) writes w12t rows [nx*128, nx*128+128), then release-signals
//   flag[e*32+nx] (+1; full at 4).
// y>=32: gemm1 m-tile; acquire-spins on flag[e*32 + n0>>7] and flag[e*32 + (n0+2048)>>7].
__global__ __launch_bounds__(256) void k_fused1(
    const float* __restrict__ w12, bf16_t* __restrict__ w12t,
    int* __restrict__ wflag,
    const bf16_t* __restrict__ xb,
    const int* __restrict__ counts, const int* __restrict__ base,
    const int* __restrict__ tile_e, const int* __restrict__ tile_m0,
    const int* __restrict__ slot_token, bf16_t* __restrict__ h) {
  __shared__ __align__(16) char lds_raw[67584];   // max(transpose 67.6K, gemm1 64K)
  const int tid = threadIdx.x;

  if (blockIdx.y < 32) {        // ---- producer: w12^T big tile ----
    int id = blockIdx.y * 32 + blockIdx.x;       // 0..1023
    int e = id >> 7, rem = id & 127;
    int ky = rem >> 5, nx = rem & 31;
    wt_tile(w12, w12t, DIM, 2 * HID, e, ky, nx, (bf16_t(*)[264])lds_raw);
    __threadfence();            // release: all this thread's w12t stores device-visible
    __syncthreads();            // all threads' fences done
    if (tid == 0) __hip_atomic_fetch_add(&wflag[e * 32 + nx], 1,
                                         __ATOMIC_RELEASE, __HIP_MEMORY_SCOPE_AGENT);
    return;
  }

  // ---- consumer: gemm1 m-tile ----
  const int ty = blockIdx.y - 32;
  const int e = tile_e[ty];
  if (e < 0) return;
  const int m0  = tile_m0[ty];
  const int cnt = counts[e];
  const int bas = base[e];
  const int n0  = blockIdx.x * 64;          // hid col base, [0,2048)

  // acquire: wait for both weight panels (W1 at n0, W2 at n0+2048)
  if (tid == 0) {
    const int f1 = e * 32 + (n0 >> 7);
    const int f2 = e * 32 + ((n0 + 2048) >> 7);
    while (__hip_atomic_load(&wflag[f1], __ATOMIC_ACQUIRE, __HIP_MEMORY_SCOPE_AGENT) < 4 ||
           __hip_atomic_load(&wflag[f2], __ATOMIC_ACQUIRE, __HIP_MEMORY_SCOPE_AGENT) < 4)
      __builtin_amdgcn_s_sleep(2);
  }
  __syncthreads();
  __threadfence();              // invalidate any stale cached lines before reading w12t
  asm volatile("" ::: "memory");

  const bf16_t* W1 = w12t + (size_t)e * (4096u * 1024u) + (size_t)n0 * 1024u;
  const bf16_t* W2 = W1 + (size_t)2048 * 1024;

  bf16_t* sA  = (bf16_t*)lds_raw;             // 2 x 128*64
  bf16_t* sB1 = sA + 2 * 128 * 64;            // 2 x 64*64
  bf16_t* sB2 = sB1 + 2 * 64 * 64;            // 2 x 64*64

  const int lane = tid & 63, wid = tid >> 6;
  const int wr = wid >> 1, wc = wid & 1;
  const int lr = lane >> 3, sw = (lane & 7) ^ lr;  // swizzled source chunk

  int tokA[4];
#pragma unroll
  for (int i = 0; i < 4; ++i) {
    int row = m0 + wid * 32 + i * 8 + lr;
    tokA[i] = slot_token[bas + (row < cnt ? row : cnt - 1)];
  }

  auto stage = [&](int p, int k0) {
#pragma unroll
    for (int i = 0; i < 4; ++i)
      gload_lds16(xb + (size_t)tokA[i] * DIM + k0 + sw * 8,
                  sA + p * 8192 + (wid * 32 + i * 8) * 64);
#pragma unroll
    for (int i = 0; i < 2; ++i) {
      int n = wid * 16 + i * 8 + lr;
      gload_lds16(W1 + (size_t)n * 1024 + k0 + sw * 8, sB1 + p * 4096 + (wid * 16 + i * 8) * 64);
      gload_lds16(W2 + (size_t)n * 1024 + k0 + sw * 8, sB2 + p * 4096 + (wid * 16 + i * 8) * 64);
    }
  };

  f32x4 acc1[4][2] = {};
  f32x4 acc2[4][2] = {};

  stage(0, 0);
  stage(1, 64);

  const int NT = DIM / 64;  // 16
  for (int t = 0; t < NT; ++t) {
    const int p = t & 1;
    if (t + 2 < NT) asm volatile("s_waitcnt vmcnt(8)" ::: "memory");
    else            asm volatile("s_waitcnt vmcnt(0)" ::: "memory");
    __builtin_amdgcn_s_barrier();
    asm volatile("" ::: "memory");
    __builtin_amdgcn_s_setprio(1);
#pragma unroll
    for (int kk = 0; kk < 2; ++kk) {
      const int g = kk * 4 + (lane >> 4);
      bf16x8 a[4], b1[2], b2[2];
#pragma unroll
      for (int mf = 0; mf < 4; ++mf) {
        int r = wr * 64 + mf * 16 + (lane & 15);
        a[mf] = *(const bf16x8*)(sA + p * 8192 + r * 64 + ((g ^ (r & 7)) << 3));
      }
#pragma unroll
      for (int nf = 0; nf < 2; ++nf) {
        int n = wc * 32 + nf * 16 + (lane & 15);
        b1[nf] = *(const bf16x8*)(sB1 + p * 4096 + n * 64 + ((g ^ (n & 7)) << 3));
        b2[nf] = *(const bf16x8*)(sB2 + p * 4096 + n * 64 + ((g ^ (n & 7)) << 3));
      }
#pragma unroll
      for (int mf = 0; mf < 4; ++mf)
#pragma unroll
        for (int nf = 0; nf < 2; ++nf) {
          acc1[mf][nf] = __builtin_amdgcn_mfma_f32_16x16x32_bf16(a[mf], b1[nf], acc1[mf][nf], 0, 0, 0);
          acc2[mf][nf] = __builtin_amdgcn_mfma_f32_16x16x32_bf16(a[mf], b2[nf], acc2[mf][nf], 0, 0, 0);
        }
    }
    __builtin_amdgcn_s_setprio(0);
    __builtin_amdgcn_sched_barrier(0);
    __builtin_amdgcn_s_barrier();
    asm volatile("" ::: "memory");
    if (t + 2 < NT) stage(p, (t + 2) * 64);
  }

#pragma unroll
  for (int mf = 0; mf < 4; ++mf)
#pragma unroll
    for (int r = 0; r < 4; ++r) {
      int m = wr * 64 + mf * 16 + ((lane >> 4) << 2) + r;
      if (m0 + m < cnt) {
        size_t rowoff = (size_t)(bas + m0 + m) * HID + n0;
#pragma unroll
        for (int nf = 0; nf < 2; ++nf) {
          int col = wc * 32 + nf * 16 + (lane & 15);
          float d1 = acc1[mf][nf][r], d2 = acc2[mf][nf][r];
          h[rowoff + col] = (bf16_t)((d1 / (1.f + __expf(-d1))) * d2);
        }
      }
    }
}

// ---------------- GEMM2: eout[slot] = wt * (h @ W3) (proven R8 form, unchanged) ----------------
__global__ __launch_bounds__(256) void k_gemm2(
    const bf16_t* __restrict__ h, const bf16_t* __restrict__ w3t,
    const int* __restrict__ counts, const int* __restrict__ base,
    const int* __restrict__ tile_e, const int* __restrict__ tile_m0,
    const float* __restrict__ slot_wt, bf16_t* __restrict__ eout) {
  const int e = tile_e[blockIdx.y];
  if (e < 0) return;
  const int m0  = tile_m0[blockIdx.y];
  const int cnt = counts[e];
  const int bas = base[e];
  const int n0 = blockIdx.x * 128;
  const bf16_t* W = w3t + (size_t)e * (1024u * 2048u);

  __shared__ bf16_t sA[2][128 * 64];
  __shared__ bf16_t sB[2][128 * 64];

  const int tid = threadIdx.x, lane = tid & 63, wid = tid >> 6;
  const int wr = wid >> 1, wc = wid & 1;
  const int lr = lane >> 3, sw = (lane & 7) ^ lr;

  int rowA[4];
#pragma unroll
  for (int i = 0; i < 4; ++i) {
    int row = m0 + wid * 32 + i * 8 + lr;
    rowA[i] = bas + (row < cnt ? row : cnt - 1);
  }

  auto stage = [&](int p, int k0) {
#pragma unroll
    for (int i = 0; i < 4; ++i) {
      int rr = wid * 32 + i * 8;
      gload_lds16(h + (size_t)rowA[i] * HID + k0 + sw * 8, &sA[p][rr * 64]);
      gload_lds16(W + (size_t)(n0 + rr + lr) * 2048 + k0 + sw * 8, &sB[p][rr * 64]);
    }
  };

  f32x4 acc[4][4] = {};

  stage(0, 0);
  stage(1, 64);

  const int NT = HID / 64;  // 32
  for (int t = 0; t < NT; ++t) {
    const int p = t & 1;
    if (t + 2 < NT) asm volatile("s_waitcnt vmcnt(8)" ::: "memory");
    else            asm volatile("s_waitcnt vmcnt(0)" ::: "memory");
    __builtin_amdgcn_s_barrier();
    asm volatile("" ::: "memory");
    __builtin_amdgcn_s_setprio(1);
#pragma unroll
    for (int kk = 0; kk < 2; ++kk) {
      const int g = kk * 4 + (lane >> 4);
      bf16x8 a[4], b[4];
#pragma unroll
      for (int mf = 0; mf < 4; ++mf) {
        int r = wr * 64 + mf * 16 + (lane & 15);
        a[mf] = *(const bf16x8*)(&sA[p][r * 64 + ((g ^ (r & 7)) << 3)]);
      }
#pragma unroll
      for (int nf = 0; nf < 4; ++nf) {
        int n = wc * 64 + nf * 16 + (lane & 15);
        b[nf] = *(const bf16x8*)(&sB[p][n * 64 + ((g ^ (n & 7)) << 3)]);
      }
#pragma unroll
      for (int mf = 0; mf < 4; ++mf)
#pragma unroll
        for (int nf = 0; nf < 4; ++nf)
          acc[mf][nf] = __builtin_amdgcn_mfma_f32_16x16x32_bf16(a[mf], b[nf], acc[mf][nf], 0, 0, 0);
    }
    __builtin_amdgcn_s_setprio(0);
    __builtin_amdgcn_sched_barrier(0);
    __builtin_amdgcn_s_barrier();
    asm volatile("" ::: "memory");
    if (t + 2 < NT) stage(p, (t + 2) * 64);
  }

#pragma unroll
  for (int mf = 0; mf < 4; ++mf)
#pragma unroll
    for (int r = 0; r < 4; ++r) {
      int m = wr * 64 + mf * 16 + ((lane >> 4) << 2) + r;
      if (m0 + m < cnt) {
        int gs = bas + m0 + m;
        float wt = slot_wt[gs];
        size_t o = (size_t)gs * DIM + n0;
#pragma unroll
        for (int nf = 0; nf < 4; ++nf) {
          int col = wc * 64 + nf * 16 + (lane & 15);
          eout[o + col] = (bf16_t)(acc[mf][nf][r] * wt);
        }
      }
    }
}

// ---------------- combine: out[t] = eout[g0] + eout[g1] ----------------
__global__ __launch_bounds__(256) void k_combine(const bf16_t* __restrict__ eout,
    const int* __restrict__ slot_of, float* __restrict__ out) {
  const int t = blockIdx.x;
  const int c = threadIdx.x * 4;
  const int g0 = slot_of[2 * t], g1 = slot_of[2 * t + 1];
  bf16x4 a = *(const bf16x4*)(eout + (size_t)g0 * DIM + c);
  bf16x4 b = *(const bf16x4*)(eout + (size_t)g1 * DIM + c);
  float4 o;
  o.x = (float)a[0] + (float)b[0];
  o.y = (float)a[1] + (float)b[1];
  o.z = (float)a[2] + (float)b[2];
  o.w = (float)a[3] + (float)b[3];
  *(float4*)(out + (size_t)t * DIM + c) = o;
}

extern "C" void kernel_launch(void* const* d_in, const int* in_sizes, int n_in,
                              void* d_out, int out_size, void* d_ws, size_t ws_size,
                              hipStream_t stream) {
  const float* x   = (const float*)d_in[0];
  const float* rw  = (const float*)d_in[1];
  const float* rb  = (const float*)d_in[2];
  const float* w12 = (const float*)d_in[3];
  const float* w3  = (const float*)d_in[4];
  float* out = (float*)d_out;
  float* aux = out + (size_t)T_TOK * DIM;

  char* ws = (char*)d_ws;
  int*   counts     = (int*)(ws + 0);
  int*   fill       = (int*)(ws + 64);
  int*   base       = (int*)(ws + 128);
  int*   wflag      = (int*)(ws + 2048);            // 256 ints, zeroed each launch
  int*   top_i      = (int*)(ws + 4096);
  float* top_w      = (float*)(ws + 4096 + 32768);
  int*   slot_token = (int*)(ws + 4096 + 65536);
  float* slot_wt    = (float*)(ws + 4096 + 98304);
  int*   slot_of    = (int*)(ws + 4096 + 131072);
  int*   tile_e     = (int*)(ws + 4096 + 163840);
  int*   tile_m0    = (int*)(ws + 4096 + 164352);
  bf16_t* xb        = (bf16_t*)(ws + 262144);                       // 8 MiB
  bf16_t* h         = (bf16_t*)(ws + 262144 + 8388608);             // 32 MiB
  bf16_t* w12t      = (bf16_t*)(ws + 262144 + 8388608 + 33554432);  // 64 MiB
  bf16_t* w3t       = (bf16_t*)((char*)w12t + 67108864);            // 32 MiB
  bf16_t* eout      = w12t;  // aliases w12t region during gemm2 (w12t dead by then)
  // peak ws usage = 142,868,480 B — identical to R12-R16 proven-safe footprint

  hipMemsetAsync(ws, 0, 4096, stream);              // counts/fill + wflag
  hipMemsetAsync(aux, 0, sizeof(float), stream);    // aux accumulator

  // prepA: w3^T (512 big-tile blocks) + router (1024)
  k_prepA<<<dim3(1536), dim3(256), 0, stream>>>(x, rw, rb, w3, xb, w3t,
                                                counts, top_i, top_w, aux);
  k_plan<<<dim3(1), dim3(64), 0, stream>>>(counts, base, tile_e, tile_m0);
  k_gather<<<dim3(T_TOK / 256), dim3(256), 0, stream>>>(top_i, top_w, base, fill,
                                                        slot_token, slot_wt, slot_of);
  // fused: y<32 = w12^T producers (1024 tiles), y>=32 = gemm1 consumers
  k_fused1<<<dim3(32, 32 + MAXT), dim3(256), 0, stream>>>(
      w12, w12t, wflag, xb, counts, base, tile_e, tile_m0, slot_token, h);
  k_gemm2<<<dim3(DIM / 128, MAXT), dim3(256), 0, stream>>>(
      h, w3t, counts, base, tile_e, tile_m0, slot_wt, eout);
  k_combine<<<dim3(T_TOK), dim3(256), 0, stream>>>(eout, slot_of, out);
}

// Round 19
// 386.014 us; speedup vs baseline: 2.2589x; 2.2589x over previous
//
#include <hip/hip_runtime.h>
#include <hip/hip_bf16.h>
#include <stdint.h>

typedef __bf16 bf16_t;
typedef __bf16 bf16x8 __attribute__((ext_vector_type(8)));
typedef __bf16 bf16x4 __attribute__((ext_vector_type(4)));
typedef float f32x4 __attribute__((ext_vector_type(4)));
typedef uint32_t u32x2 __attribute__((ext_vector_type(2)));
typedef __attribute__((address_space(3))) const uint8_t* lds3;

#define T_TOK 4096
#define DIM   1024
#define HID   2048
#define NE    8
#define MAXT  72   // max 128-row m-tiles: 8192/128 + 8

// async global->LDS, 16B per lane, LDS dest = wave-uniform base + lane*16
__device__ __forceinline__ void gload_lds16(const void* g, void* l) {
  __builtin_amdgcn_global_load_lds(
      (const __attribute__((address_space(1))) unsigned int*)g,
      (__attribute__((address_space(3))) unsigned int*)l, 16, 0, 0);
}

// hardware transpose read (cross-lane): lane CONTRIBUTES the 8B chunk at its addr;
// 16-lane group assembles a 4x16 bf16 subtile; result lane l elem j = subtile[j][l&15].
// Lane addr must be subtile_base + (l&15)*8 (8B aligned).
#define TRR(dst, a, OFF) \
  asm volatile("ds_read_b64_tr_b16 %0, %1 offset:" OFF : "=v"(dst) : "v"(a))

__device__ __forceinline__ bf16x8 mk8(u32x2 lo, u32x2 hi) {
  uint4 t; t.x = lo[0]; t.y = lo[1]; t.z = hi[0]; t.w = hi[1];
  return __builtin_bit_cast(bf16x8, t);
}

// ---------------- weight convert f32->bf16, same layout (fully coalesced) ----------------
__global__ __launch_bounds__(256) void k_conv(const float* __restrict__ w12,
    const float* __restrict__ w3, bf16_t* __restrict__ w12c, bf16_t* __restrict__ w3c) {
  const size_t N12 = 33554432ull;          // 8*1024*4096
  const size_t NT  = 50331648ull;          // + 8*2048*1024
  const size_t stride = (size_t)gridDim.x * 256 * 4;
  for (size_t i = ((size_t)blockIdx.x * 256 + threadIdx.x) * 4; i < NT; i += stride) {
    if (i < N12) {
      float4 v = *(const float4*)(w12 + i);
      bf16x4 o; o[0]=(bf16_t)v.x; o[1]=(bf16_t)v.y; o[2]=(bf16_t)v.z; o[3]=(bf16_t)v.w;
      *(bf16x4*)(w12c + i) = o;
    } else {
      size_t j = i - N12;
      float4 v = *(const float4*)(w3 + j);
      bf16x4 o; o[0]=(bf16_t)v.x; o[1]=(bf16_t)v.y; o[2]=(bf16_t)v.z; o[3]=(bf16_t)v.w;
      *(bf16x4*)(w3c + j) = o;
    }
  }
}

// ---------------- router (+ fused x->bf16): logits, sigmoid, top-2, aux ----------------
__global__ __launch_bounds__(256) void k_router(const float* __restrict__ x,
    const float* __restrict__ rw, const float* __restrict__ rb,
    int* __restrict__ counts, int* __restrict__ top_i, float* __restrict__ top_w,
    float* __restrict__ aux, bf16_t* __restrict__ xb) {
  int t = blockIdx.x * 4 + (threadIdx.x >> 6);
  int lane = threadIdx.x & 63;
  const float* xt = x + (size_t)t * DIM;
  float acc[8] = {0.f,0.f,0.f,0.f,0.f,0.f,0.f,0.f};
#pragma unroll
  for (int it = 0; it < 4; ++it) {
    int i = (it * 64 + lane) * 4;
    float4 xv = *(const float4*)(xt + i);
    bf16x4 o;
    o[0] = (bf16_t)xv.x; o[1] = (bf16_t)xv.y; o[2] = (bf16_t)xv.z; o[3] = (bf16_t)xv.w;
    *(bf16x4*)(xb + (size_t)t * DIM + i) = o;
#pragma unroll
    for (int c = 0; c < 4; ++c) {
      float v = (c == 0) ? xv.x : (c == 1) ? xv.y : (c == 2) ? xv.z : xv.w;
      float4 r0 = *(const float4*)(rw + (size_t)(i + c) * 8);
      float4 r1 = *(const float4*)(rw + (size_t)(i + c) * 8 + 4);
      acc[0] += v * r0.x; acc[1] += v * r0.y; acc[2] += v * r0.z; acc[3] += v * r0.w;
      acc[4] += v * r1.x; acc[5] += v * r1.y; acc[6] += v * r1.z; acc[7] += v * r1.w;
    }
  }
#pragma unroll
  for (int m = 32; m >= 1; m >>= 1) {
#pragma unroll
    for (int e = 0; e < 8; ++e) acc[e] += __shfl_xor(acc[e], m, 64);
  }
  if (lane == 0) {
    float s[8]; float sumsq = 0.f;
#pragma unroll
    for (int e = 0; e < 8; ++e) {
      float lg = acc[e] + rb[e];
      sumsq += lg * lg;
      s[e] = 1.f / (1.f + __expf(-lg));
    }
    int i1 = 0;
#pragma unroll
    for (int e = 1; e < 8; ++e) if (s[e] > s[i1]) i1 = e;
    int i2 = (i1 == 0) ? 1 : 0;
#pragma unroll
    for (int e = 0; e < 8; ++e) if (e != i1 && s[e] > s[i2]) i2 = e;
    float v1 = s[i1], v2 = s[i2];
    float den = v1 + v2 + 1e-6f;
    top_i[2 * t]     = i1; top_i[2 * t + 1] = i2;
    top_w[2 * t]     = v1 / den;
    top_w[2 * t + 1] = v2 / den;
    atomicAdd(&counts[i1], 1);
    atomicAdd(&counts[i2], 1);
    atomicAdd(aux, 0.01f * sumsq * (1.f / 32768.f));
  }
}

// ---------------- plan: base offsets + m-tile table ----------------
__global__ void k_plan(const int* __restrict__ counts, int* __restrict__ base,
                       int* __restrict__ tile_e, int* __restrict__ tile_m0) {
  if (threadIdx.x == 0) {
    int s = 0, nt = 0;
    for (int e = 0; e < NE; ++e) {
      base[e] = s;
      int c = counts[e];
      for (int m0 = 0; m0 < c; m0 += 128) { tile_e[nt] = e; tile_m0[nt] = m0; ++nt; }
      s += c;
    }
    for (; nt < MAXT; ++nt) tile_e[nt] = -1;
  }
}

// ---------------- gather tokens into per-expert slot lists ----------------
__global__ __launch_bounds__(256) void k_gather(const int* __restrict__ top_i,
    const float* __restrict__ top_w, const int* __restrict__ base,
    int* __restrict__ fill, int* __restrict__ slot_token, float* __restrict__ slot_wt,
    int* __restrict__ slot_of) {
  int t = blockIdx.x * 256 + threadIdx.x;
  if (t >= T_TOK) return;
#pragma unroll
  for (int j = 0; j < 2; ++j) {
    int e = top_i[2 * t + j];
    int p = atomicAdd(&fill[e], 1);
    int g = base[e] + p;
    slot_token[g] = t;
    slot_wt[g]    = top_w[2 * t + j];
    slot_of[2 * t + j] = g;
  }
}

// ---------------- GEMM1 + SwiGLU: B from [k][n] bf16 via subtiled LDS + tr reads ----------------
// B LDS: [kb 0..15][nb 0..3][4k][16n] subtiles; staged via gload with permuted per-lane src.
__global__ __launch_bounds__(256) void k_gemm1(
    const bf16_t* __restrict__ xb, const bf16_t* __restrict__ w12c,
    const int* __restrict__ counts, const int* __restrict__ base,
    const int* __restrict__ tile_e, const int* __restrict__ tile_m0,
    const int* __restrict__ slot_token, bf16_t* __restrict__ h) {
  const int e = tile_e[blockIdx.y];
  if (e < 0) return;
  const int m0  = tile_m0[blockIdx.y];
  const int cnt = counts[e];
  const int bas = base[e];
  const int n0  = blockIdx.x * 64;          // hid col base, [0,2048)
  const bf16_t* W1 = w12c + (size_t)e * (1024u * 4096u) + n0;  // [k][4096] rows
  const bf16_t* W2 = W1 + 2048;

  __shared__ bf16_t sA[2][128 * 64];
  __shared__ bf16_t sB1[2][64 * 64];
  __shared__ bf16_t sB2[2][64 * 64];

  const int tid = threadIdx.x, lane = tid & 63, wid = tid >> 6;
  const int wr = wid >> 1, wc = wid & 1;
  const int lr = lane >> 3, sw = (lane & 7) ^ lr;  // A swizzled source chunk

  int tokA[4];
#pragma unroll
  for (int i = 0; i < 4; ++i) {
    int row = m0 + wid * 32 + i * 8 + lr;
    tokA[i] = slot_token[bas + (row < cnt ? row : cnt - 1)];
  }

  // B granule decode (granule g: block b=g>>3, w=g&7 -> row kb*4+(w>>1), col nb*16+(w&1)*8)
  int brow0, bcol0, brow1, bcol1;
  { int b = tid >> 3, w = tid & 7;
    brow0 = ((b >> 2) << 2) + (w >> 1); bcol0 = (b & 3) * 16 + (w & 1) * 8; }
  { int g2 = 256 + tid; int b = g2 >> 3, w = g2 & 7;
    brow1 = ((b >> 2) << 2) + (w >> 1); bcol1 = (b & 3) * 16 + (w & 1) * 8; }

  auto stage = [&](int p, int k0) {
#pragma unroll
    for (int i = 0; i < 4; ++i)
      gload_lds16(xb + (size_t)tokA[i] * DIM + k0 + sw * 8,
                  &sA[p][(wid * 32 + i * 8) * 64]);
    gload_lds16(W1 + (size_t)(k0 + brow0) * 4096 + bcol0, &sB1[p][tid * 8]);
    gload_lds16(W1 + (size_t)(k0 + brow1) * 4096 + bcol1, &sB1[p][2048 + tid * 8]);
    gload_lds16(W2 + (size_t)(k0 + brow0) * 4096 + bcol0, &sB2[p][tid * 8]);
    gload_lds16(W2 + (size_t)(k0 + brow1) * 4096 + bcol1, &sB2[p][2048 + tid * 8]);
  };

  // tr-read lane base (bytes): kb-group*1024 + wc-nb*256 + CONTRIBUTION chunk (lane&15)*8
  const int trOff = (lane >> 4) * 1024 + wc * 256 + (lane & 15) * 8;
  lds3 bB1 = (lds3)(const uint8_t*)&sB1[0][0];
  lds3 bB2 = (lds3)(const uint8_t*)&sB2[0][0];

  f32x4 acc1[4][2] = {};
  f32x4 acc2[4][2] = {};

  stage(0, 0);
  stage(1, 64);

  const int NT = DIM / 64;  // 16
  for (int t = 0; t < NT; ++t) {
    const int p = t & 1;
    if (t + 2 < NT) asm volatile("s_waitcnt vmcnt(8)" ::: "memory");
    else            asm volatile("s_waitcnt vmcnt(0)" ::: "memory");
    __builtin_amdgcn_s_barrier();
    asm volatile("" ::: "memory");
    __builtin_amdgcn_s_setprio(1);
#pragma unroll
    for (int kk = 0; kk < 2; ++kk) {
      const int g = kk * 4 + (lane >> 4);
      bf16x8 a[4];
#pragma unroll
      for (int mf = 0; mf < 4; ++mf) {
        int r = wr * 64 + mf * 16 + (lane & 15);
        a[mf] = *(const bf16x8*)(&sA[p][r * 64 + ((g ^ (r & 7)) << 3)]);
      }
      lds3 a1 = bB1 + p * 8192 + kk * 4096 + trOff;
      lds3 a2 = bB2 + p * 8192 + kk * 4096 + trOff;
      u32x2 q0, q1, q2, q3, s0, s1, s2, s3;
      TRR(q0, a1, "0");   TRR(q1, a1, "512");
      TRR(q2, a1, "128"); TRR(q3, a1, "640");
      TRR(s0, a2, "0");   TRR(s1, a2, "512");
      TRR(s2, a2, "128"); TRR(s3, a2, "640");
      asm volatile("s_waitcnt lgkmcnt(0)" ::: "memory");
      __builtin_amdgcn_sched_barrier(0);
      bf16x8 b1f[2] = { mk8(q0, q1), mk8(q2, q3) };
      bf16x8 b2f[2] = { mk8(s0, s1), mk8(s2, s3) };
#pragma unroll
      for (int mf = 0; mf < 4; ++mf)
#pragma unroll
        for (int nf = 0; nf < 2; ++nf) {
          acc1[mf][nf] = __builtin_amdgcn_mfma_f32_16x16x32_bf16(a[mf], b1f[nf], acc1[mf][nf], 0, 0, 0);
          acc2[mf][nf] = __builtin_amdgcn_mfma_f32_16x16x32_bf16(a[mf], b2f[nf], acc2[mf][nf], 0, 0, 0);
        }
    }
    __builtin_amdgcn_s_setprio(0);
    __builtin_amdgcn_sched_barrier(0);
    __builtin_amdgcn_s_barrier();
    asm volatile("" ::: "memory");
    if (t + 2 < NT) stage(p, (t + 2) * 64);
  }

#pragma unroll
  for (int mf = 0; mf < 4; ++mf)
#pragma unroll
    for (int r = 0; r < 4; ++r) {
      int m = wr * 64 + mf * 16 + ((lane >> 4) << 2) + r;
      if (m0 + m < cnt) {
        size_t rowoff = (size_t)(bas + m0 + m) * HID + n0;
#pragma unroll
        for (int nf = 0; nf < 2; ++nf) {
          int col = wc * 32 + nf * 16 + (lane & 15);
          float d1 = acc1[mf][nf][r], d2 = acc2[mf][nf][r];
          h[rowoff + col] = (bf16_t)((d1 / (1.f + __expf(-d1))) * d2);
        }
      }
    }
}

// ---------------- GEMM2: eout = wt*(h @ W3), B from [k][n] bf16 via tr reads ----------------
// B LDS: [kb 0..15][nb 0..7][4][16] subtiles.
__global__ __launch_bounds__(256) void k_gemm2(
    const bf16_t* __restrict__ h, const bf16_t* __restrict__ w3c,
    const int* __restrict__ counts, const int* __restrict__ base,
    const int* __restrict__ tile_e, const int* __restrict__ tile_m0,
    const float* __restrict__ slot_wt, bf16_t* __restrict__ eout) {
  const int e = tile_e[blockIdx.y];
  if (e < 0) return;
  const int m0  = tile_m0[blockIdx.y];
  const int cnt = counts[e];
  const int bas = base[e];
  const int n0 = blockIdx.x * 128;
  const bf16_t* W = w3c + (size_t)e * (2048u * 1024u) + n0;   // [k][1024] rows

  __shared__ bf16_t sA[2][128 * 64];
  __shared__ bf16_t sB[2][128 * 64];

  const int tid = threadIdx.x, lane = tid & 63, wid = tid >> 6;
  const int wr = wid >> 1, wc = wid & 1;
  const int lr = lane >> 3, sw = (lane & 7) ^ lr;

  int rowA[4];
#pragma unroll
  for (int i = 0; i < 4; ++i) {
    int row = m0 + wid * 32 + i * 8 + lr;
    rowA[i] = bas + (row < cnt ? row : cnt - 1);
  }

  // B granule decode: b=g>>3 (kb=b>>3, nb=b&7), w=g&7 (r=w>>1, half=w&1)
  int br[4], bc[4];
#pragma unroll
  for (int j = 0; j < 4; ++j) {
    int g = j * 256 + tid;
    int b = g >> 3, w = g & 7;
    br[j] = ((b >> 3) << 2) + (w >> 1);
    bc[j] = (b & 7) * 16 + (w & 1) * 8;
  }

  auto stage = [&](int p, int k0) {
#pragma unroll
    for (int i = 0; i < 4; ++i)
      gload_lds16(h + (size_t)rowA[i] * HID + k0 + sw * 8,
                  &sA[p][(wid * 32 + i * 8) * 64]);
#pragma unroll
    for (int j = 0; j < 4; ++j)
      gload_lds16(W + (size_t)(k0 + br[j]) * 1024 + bc[j],
                  &sB[p][(j * 256 + tid) * 8]);
  };

  // tr lane base: kb-group*2048 + wc*512 + contribution chunk (lane&15)*8 (bytes)
  const int trOff = (lane >> 4) * 2048 + wc * 512 + (lane & 15) * 8;
  lds3 bB = (lds3)(const uint8_t*)&sB[0][0];

  f32x4 acc[4][4] = {};

  stage(0, 0);
  stage(1, 64);

  const int NT = HID / 64;  // 32
  for (int t = 0; t < NT; ++t) {
    const int p = t & 1;
    if (t + 2 < NT) asm volatile("s_waitcnt vmcnt(8)" ::: "memory");
    else            asm volatile("s_waitcnt vmcnt(0)" ::: "memory");
    __builtin_amdgcn_s_barrier();
    asm volatile("" ::: "memory");
    __builtin_amdgcn_s_setprio(1);
#pragma unroll
    for (int kk = 0; kk < 2; ++kk) {
      const int g = kk * 4 + (lane >> 4);
      bf16x8 a[4];
#pragma unroll
      for (int mf = 0; mf < 4; ++mf) {
        int r = wr * 64 + mf * 16 + (lane & 15);
        a[mf] = *(const bf16x8*)(&sA[p][r * 64 + ((g ^ (r & 7)) << 3)]);
      }
      lds3 ab = bB + p * 16384 + kk * 8192 + trOff;
      u32x2 q0, q1, q2, q3, q4, q5, q6, q7;
      TRR(q0, ab, "0");   TRR(q1, ab, "1024");
      TRR(q2, ab, "128"); TRR(q3, ab, "1152");
      TRR(q4, ab, "256"); TRR(q5, ab, "1280");
      TRR(q6, ab, "384"); TRR(q7, ab, "1408");
      asm volatile("s_waitcnt lgkmcnt(0)" ::: "memory");
      __builtin_amdgcn_sched_barrier(0);
      bf16x8 bf[4] = { mk8(q0, q1), mk8(q2, q3), mk8(q4, q5), mk8(q6, q7) };
#pragma unroll
      for (int mf = 0; mf < 4; ++mf)
#pragma unroll
        for (int nf = 0; nf < 4; ++nf)
          acc[mf][nf] = __builtin_amdgcn_mfma_f32_16x16x32_bf16(a[mf], bf[nf], acc[mf][nf], 0, 0, 0);
    }
    __builtin_amdgcn_s_setprio(0);
    __builtin_amdgcn_sched_barrier(0);
    __builtin_amdgcn_s_barrier();
    asm volatile("" ::: "memory");
    if (t + 2 < NT) stage(p, (t + 2) * 64);
  }

#pragma unroll
  for (int mf = 0; mf < 4; ++mf)
#pragma unroll
    for (int r = 0; r < 4; ++r) {
      int m = wr * 64 + mf * 16 + ((lane >> 4) << 2) + r;
      if (m0 + m < cnt) {
        int gs = bas + m0 + m;
        float wt = slot_wt[gs];
        size_t o = (size_t)gs * DIM + n0;
#pragma unroll
        for (int nf = 0; nf < 4; ++nf) {
          int col = wc * 64 + nf * 16 + (lane & 15);
          eout[o + col] = (bf16_t)(acc[mf][nf][r] * wt);
        }
      }
    }
}

// ---------------- combine: out[t] = eout[g0] + eout[g1] ----------------
__global__ __launch_bounds__(256) void k_combine(const bf16_t* __restrict__ eout,
    const int* __restrict__ slot_of, float* __restrict__ out) {
  const int t = blockIdx.x;
  const int c = threadIdx.x * 4;
  const int g0 = slot_of[2 * t], g1 = slot_of[2 * t + 1];
  bf16x4 a = *(const bf16x4*)(eout + (size_t)g0 * DIM + c);
  bf16x4 b = *(const bf16x4*)(eout + (size_t)g1 * DIM + c);
  float4 o;
  o.x = (float)a[0] + (float)b[0];
  o.y = (float)a[1] + (float)b[1];
  o.z = (float)a[2] + (float)b[2];
  o.w = (float)a[3] + (float)b[3];
  *(float4*)(out + (size_t)t * DIM + c) = o;
}

extern "C" void kernel_launch(void* const* d_in, const int* in_sizes, int n_in,
                              void* d_out, int out_size, void* d_ws, size_t ws_size,
                              hipStream_t stream) {
  const float* x   = (const float*)d_in[0];
  const float* rw  = (const float*)d_in[1];
  const float* rb  = (const float*)d_in[2];
  const float* w12 = (const float*)d_in[3];
  const float* w3  = (const float*)d_in[4];
  float* out = (float*)d_out;
  float* aux = out + (size_t)T_TOK * DIM;

  char* ws = (char*)d_ws;
  int*   counts     = (int*)(ws + 0);
  int*   fill       = (int*)(ws + 64);
  int*   base       = (int*)(ws + 128);
  int*   top_i      = (int*)(ws + 4096);
  float* top_w      = (float*)(ws + 4096 + 32768);
  int*   slot_token = (int*)(ws + 4096 + 65536);
  float* slot_wt    = (float*)(ws + 4096 + 98304);
  int*   slot_of    = (int*)(ws + 4096 + 131072);
  int*   tile_e     = (int*)(ws + 4096 + 163840);
  int*   tile_m0    = (int*)(ws + 4096 + 164352);
  bf16_t* xb        = (bf16_t*)(ws + 262144);                       // 8 MiB
  bf16_t* h         = (bf16_t*)(ws + 262144 + 8388608);             // 32 MiB
  bf16_t* w12c      = (bf16_t*)(ws + 262144 + 8388608 + 33554432);  // 64 MiB, [e][1024][4096]
  bf16_t* w3c       = (bf16_t*)((char*)w12c + 67108864);            // 32 MiB, [e][2048][1024]
  bf16_t* eout      = w12c;  // aliases w12c during gemm2 (w12c dead by then)
  // peak ws = 142,868,480 B — proven-safe footprint

  hipMemsetAsync(ws, 0, 256, stream);                 // counts/fill
  hipMemsetAsync(aux, 0, sizeof(float), stream);      // aux accumulator

  k_conv<<<dim3(2048), dim3(256), 0, stream>>>(w12, w3, w12c, w3c);
  k_router<<<dim3(T_TOK / 4), dim3(256), 0, stream>>>(x, rw, rb, counts, top_i, top_w,
                                                      aux, xb);
  k_plan<<<dim3(1), dim3(64), 0, stream>>>(counts, base, tile_e, tile_m0);
  k_gather<<<dim3(T_TOK / 256), dim3(256), 0, stream>>>(top_i, top_w, base, fill,
                                                        slot_token, slot_wt, slot_of);
  k_gemm1<<<dim3(HID / 64, MAXT), dim3(256), 0, stream>>>(
      xb, w12c, counts, base, tile_e, tile_m0, slot_token, h);
  k_gemm2<<<dim3(DIM / 128, MAXT), dim3(256), 0, stream>>>(
      h, w3c, counts, base, tile_e, tile_m0, slot_wt, eout);
  k_combine<<<dim3(T_TOK), dim3(256), 0, stream>>>(eout, slot_of, out);
}